// Round 1
// 427.774 us; speedup vs baseline: 1.0046x; 1.0046x over previous
//
#include <hip/hip_runtime.h>
#include <hip/hip_bf16.h>
#include <math.h>

// Shapes (fixed by the problem): B=32, O=1, L=2048, D=1024, D2=512.
// All inputs/outputs are float32 (verified: bf16 interpretation NaN'd,
// f32 path passed with absmax 2e-3).
#define NB 32
#define NL 2048
#define ND 1024
#define ND2 512
#define CH 32           // l-chunks per batch for k_flash
#define ROWS (NL / CH)  // 64 rows per block
#define RPW (ROWS / 4)  // 16 rows per wave
#define MSPLIT 8        // k_merge slices per batch

__device__ __forceinline__ float waveReduceSum(float v) {
    for (int off = 32; off > 0; off >>= 1) v += __shfl_down(v, off, 64);
    return v;
}

// q[b,e] = sum_d query[b,d] * W_in[e,d]; one wave per (b,e). 8192 blocks.
__global__ __launch_bounds__(256) void k_qproj(const float* __restrict__ query,
                                               const float* __restrict__ W_in,
                                               float* __restrict__ q) {
    int wave = blockIdx.x * 4 + (threadIdx.x >> 6);
    int lane = threadIdx.x & 63;
    int b = wave >> 10;
    int e = wave & 1023;
    const float4* qr = (const float4*)(query + (size_t)b * ND) + lane * 4;
    const float4* wr = (const float4*)(W_in + (size_t)e * ND) + lane * 4;
    float s = 0.f;
#pragma unroll
    for (int t = 0; t < 4; t++) {
        float4 a = qr[t], w = wr[t];
        s += a.x * w.x + a.y * w.y + a.z * w.z + a.w * w.w;
    }
    s = waveReduceSum(s);
    if (lane == 0) q[b * ND + e] = s;
}

// Single pass over context: per (b, chunk) block, per-wave online softmax +
// weighted accumulation. 4-row batches: independent dots, interleaved
// butterflies, one deferred-max rescale per batch (threshold +8 — exact after
// final normalization since partials are self-consistent in m).
__global__ __launch_bounds__(256) void k_flash(const float* __restrict__ q,
                                               const float* __restrict__ ctx,
                                               const float* __restrict__ ae,
                                               const float* __restrict__ ab,
                                               float* __restrict__ scores,
                                               float* __restrict__ pm,
                                               float* __restrict__ pZ,
                                               float* __restrict__ pacc) {
    int b = blockIdx.x >> 5;       // CH == 32
    int chunk = blockIdx.x & 31;
    int wave = threadIdx.x >> 6;
    int lane = threadIdx.x & 63;

    // q fragment: 16 consecutive floats per lane
    const float4* qp = (const float4*)(q + (size_t)b * ND) + lane * 4;
    float4 q0 = qp[0], q1 = qp[1], q2 = qp[2], q3 = qp[3];
    float aev = ae[b], abv = ab[b];

    float m = -INFINITY, Z = 0.f;
    float acc[16];
#pragma unroll
    for (int j = 0; j < 16; j++) acc[j] = 0.f;

    int l0 = chunk * ROWS + wave * RPW;
    for (int i = 0; i < RPW; i += 4) {
        const float* rowb = ctx + ((size_t)b * NL + (l0 + i)) * ND;
        float4 c[4][4];
        float s[4];
#pragma unroll
        for (int r = 0; r < 4; r++) {
            const float4* cp = (const float4*)(rowb + (size_t)r * ND) + lane * 4;
            c[r][0] = cp[0]; c[r][1] = cp[1]; c[r][2] = cp[2]; c[r][3] = cp[3];
            s[r] = c[r][0].x*q0.x + c[r][0].y*q0.y + c[r][0].z*q0.z + c[r][0].w*q0.w
                 + c[r][1].x*q1.x + c[r][1].y*q1.y + c[r][1].z*q1.z + c[r][1].w*q1.w
                 + c[r][2].x*q2.x + c[r][2].y*q2.y + c[r][2].z*q2.z + c[r][2].w*q2.w
                 + c[r][3].x*q3.x + c[r][3].y*q3.y + c[r][3].z*q3.z + c[r][3].w*q3.w;
        }
        // 4 interleaved butterflies: latency of each shfl step hidden 4-way
#pragma unroll
        for (int off = 32; off > 0; off >>= 1) {
#pragma unroll
            for (int r = 0; r < 4; r++) s[r] += __shfl_xor(s[r], off, 64);
        }
        if (lane == 0)
            *(float4*)(scores + (size_t)b * NL + l0 + i) =
                make_float4(s[0], s[1], s[2], s[3]);

        float bmax = fmaxf(fmaxf(s[0], s[1]), fmaxf(s[2], s[3]));
        if (bmax > m + 8.f) {              // deferred-max: rescale rarely
            float sc = __expf(m - bmax);   // 0 on first batch (m = -inf)
            m = bmax;
            Z *= sc;
#pragma unroll
            for (int j = 0; j < 16; j++) acc[j] *= sc;
        }
#pragma unroll
        for (int r = 0; r < 4; r++) {
            int l = l0 + i + r;
            float bt = __expf(-abv * (float)(NL - 1 - l));
            float p = __expf(s[r] - m);    // bounded by e^8
            float k2 = p * aev * bt;
            Z += p;
#pragma unroll
            for (int t = 0; t < 4; t++) {
                float4 cv = c[r][t];
                acc[t * 4 + 0] += p * cv.x + k2 * fmaxf(cv.x, 0.f);
                acc[t * 4 + 1] += p * cv.y + k2 * fmaxf(cv.y, 0.f);
                acc[t * 4 + 2] += p * cv.z + k2 * fmaxf(cv.z, 0.f);
                acc[t * 4 + 3] += p * cv.w + k2 * fmaxf(cv.w, 0.f);
            }
        }
    }

    // merge the 4 waves of this block
    __shared__ float sacc[4 * ND];   // 16 KB
    __shared__ float sm[4], sZ[4];
#pragma unroll
    for (int j = 0; j < 16; j++) sacc[wave * ND + lane * 16 + j] = acc[j];
    if (lane == 0) { sm[wave] = m; sZ[wave] = Z; }
    __syncthreads();

    int tid = threadIdx.x;
    float m0 = sm[0], m1 = sm[1], m2 = sm[2], m3 = sm[3];
    float mb = fmaxf(fmaxf(m0, m1), fmaxf(m2, m3));
    float e0 = __expf(m0 - mb), e1 = __expf(m1 - mb),
          e2 = __expf(m2 - mb), e3 = __expf(m3 - mb);
    int d = tid * 4;
    float4 v;
    v.x = e0*sacc[0*ND+d+0] + e1*sacc[1*ND+d+0] + e2*sacc[2*ND+d+0] + e3*sacc[3*ND+d+0];
    v.y = e0*sacc[0*ND+d+1] + e1*sacc[1*ND+d+1] + e2*sacc[2*ND+d+1] + e3*sacc[3*ND+d+1];
    v.z = e0*sacc[0*ND+d+2] + e1*sacc[1*ND+d+2] + e2*sacc[2*ND+d+2] + e3*sacc[3*ND+d+2];
    v.w = e0*sacc[0*ND+d+3] + e1*sacc[1*ND+d+3] + e2*sacc[2*ND+d+3] + e3*sacc[3*ND+d+3];
    *(float4*)(pacc + ((size_t)(b * CH + chunk)) * ND + d) = v;
    if (tid == 0) {
        pm[b * CH + chunk] = mb;
        pZ[b * CH + chunk] = e0*sZ[0] + e1*sZ[1] + e2*sZ[2] + e3*sZ[3];
    }
}

// Per-b merge of CH partials -> mixed[b,:], plus exact attn output.
// Split MSPLIT ways per batch (grid 32 -> 256 blocks) for occupancy:
// each slice redundantly computes the cheap (m,Z) merge, then owns
// ND/MSPLIT mixed columns and NL/MSPLIT attn elements.
__global__ __launch_bounds__(256) void k_merge(const float* __restrict__ pm,
                                               const float* __restrict__ pZ,
                                               const float* __restrict__ pacc,
                                               const float* __restrict__ scores,
                                               float* __restrict__ mixed,
                                               float* __restrict__ attn_out) {
    int b = blockIdx.x >> 3;       // MSPLIT == 8
    int slice = blockIdx.x & 7;
    int tid = threadIdx.x;
    __shared__ float ew[CH];
    __shared__ float smg, sinvZ;
    if (tid == 0) {
        float mg = -INFINITY;
        for (int i = 0; i < CH; i++) mg = fmaxf(mg, pm[b * CH + i]);
        float Zg = 0.f;
        for (int i = 0; i < CH; i++) Zg += __expf(pm[b * CH + i] - mg) * pZ[b * CH + i];
        smg = mg; sinvZ = 1.f / Zg;
    }
    __syncthreads();
    float mg = smg, invZ = sinvZ;
    if (tid < CH) ew[tid] = __expf(pm[b * CH + tid] - mg) * invZ;  // invZ folded
    __syncthreads();

    // mixed slice: ND/MSPLIT = 128 columns = 32 float4, threads 0..31
    if (tid < 32) {
        int d = slice * (ND / MSPLIT) + tid * 4;
        float4 accv = {0.f, 0.f, 0.f, 0.f};
        for (int i = 0; i < CH; i++) {
            float4 pv = *(const float4*)(pacc + ((size_t)(b * CH + i)) * ND + d);
            float e = ew[i];
            accv.x += e * pv.x; accv.y += e * pv.y;
            accv.z += e * pv.z; accv.w += e * pv.w;
        }
        *(float4*)(mixed + (size_t)b * ND + d) = accv;   // already normalized
    }

    // attn slice: NL/MSPLIT = 256 elements, one per thread
    int l = slice * (NL / MSPLIT) + tid;
    attn_out[b * NL + l] = __expf(scores[b * NL + l] - mg) * invZ;
}

// out[b,e] = tanh( [mixed,q][b,:] . W_out[e,:] ); one wave per (b,e). 4096 blocks.
__global__ __launch_bounds__(256) void k_out(const float* __restrict__ mixed,
                                             const float* __restrict__ q,
                                             const float* __restrict__ W_out,
                                             float* __restrict__ out) {
    int wave = blockIdx.x * 4 + (threadIdx.x >> 6);
    int lane = threadIdx.x & 63;
    int b = wave >> 9;
    int e = wave & 511;
    int c0 = lane * 32;   // 32 consecutive floats of the 2048-dim combined vec
    const float* src = (lane < 32) ? (mixed + (size_t)b * ND + c0)
                                   : (q + (size_t)b * ND + c0 - ND);
    const float4* wr = (const float4*)(W_out + (size_t)e * 2 * ND + c0);
    const float4* sp = (const float4*)src;
    float s = 0.f;
#pragma unroll
    for (int t = 0; t < 8; t++) {
        float4 w = wr[t], x = sp[t];
        s += w.x * x.x + w.y * x.y + w.z * x.z + w.w * x.w;
    }
    s = waveReduceSum(s);
    if (lane == 0) out[b * ND2 + e] = tanhf(s);
}

extern "C" void kernel_launch(void* const* d_in, const int* in_sizes, int n_in,
                              void* d_out, int out_size, void* d_ws, size_t ws_size,
                              hipStream_t stream) {
    const float* query = (const float*)d_in[0];
    const float* ctx   = (const float*)d_in[1];
    const float* W_in  = (const float*)d_in[2];
    const float* W_out = (const float*)d_in[3];
    const float* ae    = (const float*)d_in[4];
    const float* ab    = (const float*)d_in[5];
    float* out = (float*)d_out;                    // [NB, ND2]
    float* attn_out = out + (size_t)NB * ND2;      // [NB, NL]

    float* ws     = (float*)d_ws;
    float* q      = ws;                        // 32768
    float* scores = ws + 32768;                // 65536
    float* pm     = ws + 98304;                // 1024
    float* pZ     = ws + 99328;                // 1024
    float* pacc   = ws + 100352;               // NB*CH*ND = 1048576
    float* mixed  = ws + 1148928;              // 32768

    k_qproj<<<8192, 256, 0, stream>>>(query, W_in, q);
    k_flash<<<NB * CH, 256, 0, stream>>>(q, ctx, ae, ab, scores, pm, pZ, pacc);
    k_merge<<<NB * MSPLIT, 256, 0, stream>>>(pm, pZ, pacc, scores, mixed, attn_out);
    k_out<<<4096, 256, 0, stream>>>(mixed, q, W_out, out);
}

// Round 2
// 421.156 us; speedup vs baseline: 1.0204x; 1.0157x over previous
//
#include <hip/hip_runtime.h>
#include <hip/hip_bf16.h>
#include <math.h>

// Shapes (fixed by the problem): B=32, O=1, L=2048, D=1024, D2=512.
// All inputs/outputs are float32 (verified: bf16 interpretation NaN'd,
// f32 path passed with absmax 2e-3).
#define NB 32
#define NL 2048
#define ND 1024
#define ND2 512
#define CH 32           // l-chunks per batch for k_flash
#define ROWS (NL / CH)  // 64 rows per block
#define RPW (ROWS / 4)  // 16 rows per wave
#define MSPLIT 8        // k_merge slices per batch

__device__ __forceinline__ float dot4(float4 a, float4 b) {
    return a.x * b.x + a.y * b.y + a.z * b.z + a.w * b.w;
}

// q[b,e] = sum_d query[b,d] * W_in[e,d].
// One wave per e-row of W_in, held in registers; all 32 batches computed
// against it (W_in read exactly once from HBM; query is L2-hot 128 KB).
// 256 blocks x 4 waves. 32 independent reduce chains interleave the shfl
// latency.
__global__ __launch_bounds__(256) void k_qproj(const float* __restrict__ query,
                                               const float* __restrict__ W_in,
                                               float* __restrict__ q) {
    int wave = threadIdx.x >> 6;
    int lane = threadIdx.x & 63;
    int e = blockIdx.x * 4 + wave;
    const float4* wr = (const float4*)(W_in + (size_t)e * ND) + lane * 4;
    float4 w0 = wr[0], w1 = wr[1], w2 = wr[2], w3 = wr[3];
    float s[NB];
#pragma unroll
    for (int b = 0; b < NB; b++) {
        const float4* qr = (const float4*)(query + (size_t)b * ND) + lane * 4;
        s[b] = dot4(qr[0], w0) + dot4(qr[1], w1) + dot4(qr[2], w2) + dot4(qr[3], w3);
    }
#pragma unroll
    for (int off = 32; off > 0; off >>= 1) {
#pragma unroll
        for (int b = 0; b < NB; b++) s[b] += __shfl_down(s[b], off, 64);
    }
    if (lane == 0) {
#pragma unroll
        for (int b = 0; b < NB; b++) q[b * ND + e] = s[b];
    }
}

// Single pass over context: per (b, chunk) block, per-wave online softmax +
// weighted accumulation. 4-row batches: independent dots, interleaved
// butterflies, one deferred-max rescale per batch (threshold +8 — exact after
// final normalization since partials are self-consistent in m).
__global__ __launch_bounds__(256) void k_flash(const float* __restrict__ q,
                                               const float* __restrict__ ctx,
                                               const float* __restrict__ ae,
                                               const float* __restrict__ ab,
                                               float* __restrict__ scores,
                                               float* __restrict__ pm,
                                               float* __restrict__ pZ,
                                               float* __restrict__ pacc) {
    int b = blockIdx.x >> 5;       // CH == 32
    int chunk = blockIdx.x & 31;
    int wave = threadIdx.x >> 6;
    int lane = threadIdx.x & 63;

    // q fragment: 16 consecutive floats per lane
    const float4* qp = (const float4*)(q + (size_t)b * ND) + lane * 4;
    float4 q0 = qp[0], q1 = qp[1], q2 = qp[2], q3 = qp[3];
    float aev = ae[b], abv = ab[b];

    float m = -INFINITY, Z = 0.f;
    float acc[16];
#pragma unroll
    for (int j = 0; j < 16; j++) acc[j] = 0.f;

    int l0 = chunk * ROWS + wave * RPW;
    for (int i = 0; i < RPW; i += 4) {
        const float* rowb = ctx + ((size_t)b * NL + (l0 + i)) * ND;
        float4 c[4][4];
        float s[4];
#pragma unroll
        for (int r = 0; r < 4; r++) {
            const float4* cp = (const float4*)(rowb + (size_t)r * ND) + lane * 4;
            c[r][0] = cp[0]; c[r][1] = cp[1]; c[r][2] = cp[2]; c[r][3] = cp[3];
            s[r] = dot4(c[r][0], q0) + dot4(c[r][1], q1)
                 + dot4(c[r][2], q2) + dot4(c[r][3], q3);
        }
        // 4 interleaved butterflies: latency of each shfl step hidden 4-way
#pragma unroll
        for (int off = 32; off > 0; off >>= 1) {
#pragma unroll
            for (int r = 0; r < 4; r++) s[r] += __shfl_xor(s[r], off, 64);
        }
        if (lane == 0)
            *(float4*)(scores + (size_t)b * NL + l0 + i) =
                make_float4(s[0], s[1], s[2], s[3]);

        float bmax = fmaxf(fmaxf(s[0], s[1]), fmaxf(s[2], s[3]));
        if (bmax > m + 8.f) {              // deferred-max: rescale rarely
            float sc = __expf(m - bmax);   // 0 on first batch (m = -inf)
            m = bmax;
            Z *= sc;
#pragma unroll
            for (int j = 0; j < 16; j++) acc[j] *= sc;
        }
#pragma unroll
        for (int r = 0; r < 4; r++) {
            int l = l0 + i + r;
            float bt = __expf(-abv * (float)(NL - 1 - l));
            float p = __expf(s[r] - m);    // bounded by e^8
            float k2 = p * aev * bt;
            Z += p;
#pragma unroll
            for (int t = 0; t < 4; t++) {
                float4 cv = c[r][t];
                acc[t * 4 + 0] += p * cv.x + k2 * fmaxf(cv.x, 0.f);
                acc[t * 4 + 1] += p * cv.y + k2 * fmaxf(cv.y, 0.f);
                acc[t * 4 + 2] += p * cv.z + k2 * fmaxf(cv.z, 0.f);
                acc[t * 4 + 3] += p * cv.w + k2 * fmaxf(cv.w, 0.f);
            }
        }
    }

    // merge the 4 waves of this block
    __shared__ float sacc[4 * ND];   // 16 KB
    __shared__ float sm[4], sZ[4];
#pragma unroll
    for (int j = 0; j < 16; j++) sacc[wave * ND + lane * 16 + j] = acc[j];
    if (lane == 0) { sm[wave] = m; sZ[wave] = Z; }
    __syncthreads();

    int tid = threadIdx.x;
    float m0 = sm[0], m1 = sm[1], m2 = sm[2], m3 = sm[3];
    float mb = fmaxf(fmaxf(m0, m1), fmaxf(m2, m3));
    float e0 = __expf(m0 - mb), e1 = __expf(m1 - mb),
          e2 = __expf(m2 - mb), e3 = __expf(m3 - mb);
    int d = tid * 4;
    float4 v;
    v.x = e0*sacc[0*ND+d+0] + e1*sacc[1*ND+d+0] + e2*sacc[2*ND+d+0] + e3*sacc[3*ND+d+0];
    v.y = e0*sacc[0*ND+d+1] + e1*sacc[1*ND+d+1] + e2*sacc[2*ND+d+1] + e3*sacc[3*ND+d+1];
    v.z = e0*sacc[0*ND+d+2] + e1*sacc[1*ND+d+2] + e2*sacc[2*ND+d+2] + e3*sacc[3*ND+d+2];
    v.w = e0*sacc[0*ND+d+3] + e1*sacc[1*ND+d+3] + e2*sacc[2*ND+d+3] + e3*sacc[3*ND+d+3];
    *(float4*)(pacc + ((size_t)(b * CH + chunk)) * ND + d) = v;
    if (tid == 0) {
        pm[b * CH + chunk] = mb;
        pZ[b * CH + chunk] = e0*sZ[0] + e1*sZ[1] + e2*sZ[2] + e3*sZ[3];
    }
}

// Per-b merge of CH partials -> mixed[b,:], plus exact attn output.
// Split MSPLIT ways per batch (grid 256 blocks) for occupancy.
__global__ __launch_bounds__(256) void k_merge(const float* __restrict__ pm,
                                               const float* __restrict__ pZ,
                                               const float* __restrict__ pacc,
                                               const float* __restrict__ scores,
                                               float* __restrict__ mixed,
                                               float* __restrict__ attn_out) {
    int b = blockIdx.x >> 3;       // MSPLIT == 8
    int slice = blockIdx.x & 7;
    int tid = threadIdx.x;
    __shared__ float ew[CH];
    __shared__ float smg, sinvZ;
    if (tid == 0) {
        float mg = -INFINITY;
        for (int i = 0; i < CH; i++) mg = fmaxf(mg, pm[b * CH + i]);
        float Zg = 0.f;
        for (int i = 0; i < CH; i++) Zg += __expf(pm[b * CH + i] - mg) * pZ[b * CH + i];
        smg = mg; sinvZ = 1.f / Zg;
    }
    __syncthreads();
    float mg = smg, invZ = sinvZ;
    if (tid < CH) ew[tid] = __expf(pm[b * CH + tid] - mg) * invZ;  // invZ folded
    __syncthreads();

    // mixed slice: ND/MSPLIT = 128 columns = 32 float4, threads 0..31
    if (tid < 32) {
        int d = slice * (ND / MSPLIT) + tid * 4;
        float4 accv = {0.f, 0.f, 0.f, 0.f};
        for (int i = 0; i < CH; i++) {
            float4 pv = *(const float4*)(pacc + ((size_t)(b * CH + i)) * ND + d);
            float e = ew[i];
            accv.x += e * pv.x; accv.y += e * pv.y;
            accv.z += e * pv.z; accv.w += e * pv.w;
        }
        *(float4*)(mixed + (size_t)b * ND + d) = accv;   // already normalized
    }

    // attn slice: NL/MSPLIT = 256 elements, one per thread
    int l = slice * (NL / MSPLIT) + tid;
    attn_out[b * NL + l] = __expf(scores[b * NL + l] - mg) * invZ;
}

// out[b,e] = tanh( [mixed,q][b,:] . W_out[e,:] ).
// One wave holds its 32-float W_out slice in registers and computes 16
// batches against it (W_out read once from HBM; mixed/q are L2-hot).
// 256 blocks x 4 waves = 2 e-rows x 2 batch-halves per block.
__global__ __launch_bounds__(256) void k_out(const float* __restrict__ mixed,
                                             const float* __restrict__ q,
                                             const float* __restrict__ W_out,
                                             float* __restrict__ out) {
    int wave = threadIdx.x >> 6;
    int lane = threadIdx.x & 63;
    int e = blockIdx.x * 2 + (wave >> 1);
    int bh = (wave & 1) * 16;           // this wave's 16 batches
    int c0 = lane * 32;                 // 32 floats of the 2048-dim combined
    const float4* wr = (const float4*)(W_out + (size_t)e * 2 * ND + c0);
    float4 w[8];
#pragma unroll
    for (int t = 0; t < 8; t++) w[t] = wr[t];
    const float* base = (lane < 32) ? (mixed + c0) : (q + c0 - ND);
    float s[16];
#pragma unroll
    for (int bi = 0; bi < 16; bi++) {
        const float4* sp = (const float4*)(base + (size_t)(bh + bi) * ND);
        float a = 0.f;
#pragma unroll
        for (int t = 0; t < 8; t++) a += dot4(sp[t], w[t]);
        s[bi] = a;
    }
#pragma unroll
    for (int off = 32; off > 0; off >>= 1) {
#pragma unroll
        for (int bi = 0; bi < 16; bi++) s[bi] += __shfl_down(s[bi], off, 64);
    }
    if (lane == 0) {
#pragma unroll
        for (int bi = 0; bi < 16; bi++) out[(bh + bi) * ND2 + e] = tanhf(s[bi]);
    }
}

extern "C" void kernel_launch(void* const* d_in, const int* in_sizes, int n_in,
                              void* d_out, int out_size, void* d_ws, size_t ws_size,
                              hipStream_t stream) {
    const float* query = (const float*)d_in[0];
    const float* ctx   = (const float*)d_in[1];
    const float* W_in  = (const float*)d_in[2];
    const float* W_out = (const float*)d_in[3];
    const float* ae    = (const float*)d_in[4];
    const float* ab    = (const float*)d_in[5];
    float* out = (float*)d_out;                    // [NB, ND2]
    float* attn_out = out + (size_t)NB * ND2;      // [NB, NL]

    float* ws     = (float*)d_ws;
    float* q      = ws;                        // 32768
    float* scores = ws + 32768;                // 65536
    float* pm     = ws + 98304;                // 1024
    float* pZ     = ws + 99328;                // 1024
    float* pacc   = ws + 100352;               // NB*CH*ND = 1048576
    float* mixed  = ws + 1148928;              // 32768

    k_qproj<<<256, 256, 0, stream>>>(query, W_in, q);
    k_flash<<<NB * CH, 256, 0, stream>>>(q, ctx, ae, ab, scores, pm, pZ, pacc);
    k_merge<<<NB * MSPLIT, 256, 0, stream>>>(pm, pZ, pacc, scores, mixed, attn_out);
    k_out<<<256, 256, 0, stream>>>(mixed, q, W_out, out);
}